// Round 4
// baseline (466.560 us; speedup 1.0000x reference)
//
#include <hip/hip_runtime.h>
#include <hip/hip_bf16.h>

typedef unsigned short u16;
typedef __bf16 bf16x8 __attribute__((ext_vector_type(8)));
typedef float f32x4 __attribute__((ext_vector_type(4)));

static __device__ __forceinline__ u16 f2b(float f) {
    __hip_bfloat16 h = __float2bfloat16(f);
    union { __hip_bfloat16 b; u16 u; } c;
    c.b = h;
    return c.u;
}

// fp32 -> bf16 bits, 8 elements per thread-iter
__global__ void cvt_f32_to_bf16(const float* __restrict__ in, u16* __restrict__ out, long n8) {
    long i = (long)blockIdx.x * blockDim.x + threadIdx.x;
    long stride = (long)gridDim.x * blockDim.x;
    for (long v = i; v < n8; v += stride) {
        const float4* p = reinterpret_cast<const float4*>(in) + 2 * v;
        float4 a = p[0];
        float4 b = p[1];
        uint4 o;
        o.x = (unsigned)f2b(a.x) | ((unsigned)f2b(a.y) << 16);
        o.y = (unsigned)f2b(a.z) | ((unsigned)f2b(a.w) << 16);
        o.z = (unsigned)f2b(b.x) | ((unsigned)f2b(b.y) << 16);
        o.w = (unsigned)f2b(b.z) | ((unsigned)f2b(b.w) << 16);
        reinterpret_cast<uint4*>(out)[v] = o;
    }
}

// W[K][N] fp32 -> Wt[N][K] bf16 bits, 32x32 LDS-tiled transpose
__global__ void transpose_cvt(const float* __restrict__ w, u16* __restrict__ wt, int K, int N) {
    __shared__ float tile[32][33];
    int bn = blockIdx.x * 32;
    int bk = blockIdx.y * 32;
    int tx = threadIdx.x & 31;
    int ty = threadIdx.x >> 5;
#pragma unroll
    for (int i = 0; i < 32; i += 8)
        tile[ty + i][tx] = w[(long)(bk + ty + i) * N + bn + tx];
    __syncthreads();
#pragma unroll
    for (int i = 0; i < 32; i += 8)
        wt[(long)(bn + ty + i) * K + bk + tx] = f2b(tile[tx][ty + i]);
}

static __device__ __forceinline__ void gl_lds16(const u16* g, u16* l) {
    __builtin_amdgcn_global_load_lds(
        (const __attribute__((address_space(1))) void*)g,
        (__attribute__((address_space(3))) void*)l, 16, 0, 0);
}

// ---------------------------------------------------------------------------
// 256x256 pipelined 4-phase bf16 GEMM. C = A[8192][4096] * Wt[4096][4096]^T
// 512 threads = 8 waves (2M x 4N), per-wave 128x64, BK=64, 64 K-tiles.
// R4 change: ds_reads for phase P+1 issued BEFORE MFMA(P) (separate reg sets)
// so LDS service overlaps the MFMA epochs; 1 barrier/phase; counted vmcnt(2)
// moved to p2-end so p3 prefetches the NEXT tile's A03+b01 reads under MFMA.
// Hazard ledger:
//   RAW staging: vmcnt(2)@p2-end drains B(T+1)+A(T+1) (FIFO leaves B(T+2)h0
//     only) + barrier -> p3's next-tile reads safe.
//   WAR STG-B(T+2)->CB-B: issued after p1-end barrier > all waves consumed
//     b01(p0 MFMA) and b23(p1 MFMA) -> reads served. STG-A(T+1)->OB-A: OB-A
//     last read in tile T-1 (prefetch before its p3 MFMA), boundary barrier.
//   Reg WAR: b01 double-buffered (b01a/b01b, tile parity); a03/a47/b23 single.
// T2 swizzle unchanged (3-bit XOR, conflicts measured 0). T1 XCD swizzle kept.
// ---------------------------------------------------------------------------
#define GK 4096L

#define STG(srcbase, dstbase, hh, ktel)                                              \
    gl_lds16((srcbase) + (long)((hh) * 128) * GK + (ktel), (u16*)((dstbase) + (hh) * 16384)); \
    gl_lds16((srcbase) + (long)((hh) * 128 + 64) * GK + (ktel), (u16*)((dstbase) + (hh) * 16384 + 8192));

#define SCHED0 __builtin_amdgcn_sched_barrier(0);
#define PRIO1 __builtin_amdgcn_s_setprio(1);
#define PRIO0 __builtin_amdgcn_s_setprio(0);
#define BAR   __builtin_amdgcn_s_barrier();

#define RD_A03(buf)                                                                  \
    _Pragma("unroll") for (int mi = 0; mi < 4; ++mi)                                 \
        _Pragma("unroll") for (int kk = 0; kk < 2; ++kk)                             \
            a03[mi][kk] = *(const bf16x8*)((buf) + abase + mi * 2048 + (lcol ^ (kk * 64)));
#define RD_A47(buf)                                                                  \
    _Pragma("unroll") for (int mi = 0; mi < 4; ++mi)                                 \
        _Pragma("unroll") for (int kk = 0; kk < 2; ++kk)                             \
            a47[mi][kk] = *(const bf16x8*)((buf) + abase + (mi + 4) * 2048 + (lcol ^ (kk * 64)));
#define RD_B23(buf)                                                                  \
    _Pragma("unroll") for (int ni = 0; ni < 2; ++ni)                                 \
        _Pragma("unroll") for (int kk = 0; kk < 2; ++kk)                             \
            b23[ni][kk] = *(const bf16x8*)((buf) + bbase + (ni + 2) * 2048 + (lcol ^ (kk * 64)));
#define RD_B01(buf, DST)                                                             \
    _Pragma("unroll") for (int ni = 0; ni < 2; ++ni)                                 \
        _Pragma("unroll") for (int kk = 0; kk < 2; ++kk)                             \
            DST[ni][kk] = *(const bf16x8*)((buf) + bbase + ni * 2048 + (lcol ^ (kk * 64)));

#define MFMA_Q(AR, BR, MO, NO)                                                       \
    _Pragma("unroll") for (int mi = 0; mi < 4; ++mi)                                 \
        _Pragma("unroll") for (int ni = 0; ni < 2; ++ni)                             \
            _Pragma("unroll") for (int kk = 0; kk < 2; ++kk)                         \
                acc[(MO) + mi][(NO) + ni] = __builtin_amdgcn_mfma_f32_16x16x32_bf16( \
                    AR[mi][kk], BR[ni][kk], acc[(MO) + mi][(NO) + ni], 0, 0, 0);

// VMP is a string literal: counted vmcnt at p2-end.
#define KTILE(CB, OB, B01C, B01N, SA, SB, VMP, PF, KTA, KTB) do {                    \
    char* cb = shb + (CB) * 65536;                                                   \
    char* nb = shb + (OB) * 65536;                                                   \
    /* p0: reads(p1)=b23 | STG-A h0 | MFMA(p0): a03 x b01c -> acc[0..3][0..1] */     \
    RD_B23(cb)                                                                       \
    if (SA) { STG(Asrc, ldsAt + (OB) * 65536, 0, KTA) }                              \
    SCHED0 PRIO1                                                                     \
    MFMA_Q(a03, B01C, 0, 0)                                                          \
    PRIO0 SCHED0 BAR                                                                 \
    /* p1: reads(p2)=a47 | STG-A h1 | MFMA(p1): a03 x b23 -> acc[0..3][2..3] */      \
    RD_A47(cb)                                                                       \
    if (SA) { STG(Asrc, ldsAt + (OB) * 65536, 1, KTA) }                              \
    SCHED0 PRIO1                                                                     \
    MFMA_Q(a03, b23, 0, 2)                                                           \
    PRIO0 SCHED0 BAR                                                                 \
    /* p2: STG-B h0 | MFMA(p2): a47 x b23 -> acc[4..7][2..3] | vmcnt + bar */        \
    if (SB) { STG(Bsrc, ldsBt + (CB) * 65536, 0, KTB) }                              \
    SCHED0 PRIO1                                                                     \
    MFMA_Q(a47, b23, 4, 2)                                                           \
    PRIO0 SCHED0                                                                     \
    asm volatile("s_waitcnt vmcnt(" VMP ")" ::: "memory");                           \
    BAR                                                                              \
    /* p3: prefetch next-tile a03+b01 | STG-B h1 | MFMA(p3): a47 x b01c */           \
    if (PF) { RD_A03(nb) RD_B01(nb, B01N) }                                          \
    if (SB) { STG(Bsrc, ldsBt + (CB) * 65536, 1, KTB) }                              \
    SCHED0 PRIO1                                                                     \
    MFMA_Q(a47, B01C, 4, 0)                                                          \
    PRIO0 SCHED0 BAR                                                                 \
} while (0)

__global__ __launch_bounds__(512, 2) void gemm_bf16_256(
    const u16* __restrict__ A, const u16* __restrict__ Bt, float* __restrict__ C) {
    __shared__ __align__(16) u16 sh[2][2][256][64];   // [buf][A/B][row][col] = 128 KiB
    char* shb = (char*)&sh[0][0][0][0];

    const int t = threadIdx.x;
    const int lane = t & 63;
    const int wid = t >> 6;
    const int wr = wid >> 2;   // 0..1
    const int wc = wid & 3;    // 0..3

    // T1: bijective XCD swizzle (512 wgs, 512 % 8 == 0)
    const int bid = blockIdx.x;
    const int wg = (bid & 7) * 64 + (bid >> 3);
    const int tm = wg >> 4;          // 0..31
    const int tn = wg & 15;          // 0..15

    // staging source: thread t -> LDS physical (row = t>>3, colblk = t&7);
    // physical colblk holds logical (t&7) ^ (row&7)  [T2 involution]
    const int srow = t >> 3;
    const int scol = (((t & 7) ^ ((t >> 3) & 7)) * 8);
    const u16* Asrc = A + (long)(tm * 256 + srow) * GK + scol;
    const u16* Bsrc = Bt + (long)(tn * 256 + srow) * GK + scol;
    char* ldsAt = shb + t * 16;
    char* ldsBt = shb + 32768 + t * 16;

    // ds_read lane addressing: same involution; K-half folds in via ^(kk*64)
    const int lrow = lane & 15;
    const int lcol = (((lane >> 4) ^ (lrow & 7)) << 4);
    const int abase = (wr * 128 + lrow) * 128;
    const int bbase = 32768 + (wc * 64 + lrow) * 128;

    f32x4 acc[8][4] = {};
    bf16x8 a03[4][2], a47[4][2], b23[2][2], b01a[2][2], b01b[2][2];

    // prologue: B(0)->buf0, A(0)->buf0, B(1)->buf1 (12 loads);
    // vmcnt(4) leaves B(1)'s 4 in flight -> A(0),B(0) resident.
    STG(Bsrc, ldsBt, 0, 0)
    STG(Bsrc, ldsBt, 1, 0)
    STG(Asrc, ldsAt, 0, 0)
    STG(Asrc, ldsAt, 1, 0)
    STG(Bsrc, ldsBt + 65536, 0, 64)
    STG(Bsrc, ldsBt + 65536, 1, 64)
    asm volatile("s_waitcnt vmcnt(4)" ::: "memory");
    BAR
    // pre-issue tile0 p0 reads
    RD_A03(shb)
    RD_B01(shb, b01a)

    // tiles 0..61 (pairs), then t62 (stage A(63) only, vmcnt 0), t63 (drain)
#pragma unroll 1
    for (int it = 0; it < 31; ++it) {
        const long kt = (long)it * 128;
        KTILE(0, 1, b01a, b01b, 1, 1, "2", 1, kt + 64, kt + 128);
        KTILE(1, 0, b01b, b01a, 1, 1, "2", 1, kt + 128, kt + 192);
    }
    KTILE(0, 1, b01a, b01b, 1, 0, "0", 1, 4032, 0);
    KTILE(1, 0, b01b, b01a, 0, 0, "0", 0, 0, 0);

    // epilogue: C/D layout col=lane&15, row=(lane>>4)*4+j
    const int crow = (lane >> 4) * 4;
    const int ccol = lane & 15;
    float* Cp = C + (long)(tm * 256 + wr * 128 + crow) * 4096 + tn * 256 + wc * 64 + ccol;
#pragma unroll
    for (int mi = 0; mi < 8; ++mi) {
#pragma unroll
        for (int j = 0; j < 4; ++j) {
            float* r = Cp + (long)(mi * 16 + j) * 4096;
#pragma unroll
            for (int ni = 0; ni < 4; ++ni)
                r[ni * 16] = acc[mi][ni][j];
        }
    }
}

// fallback (only if ws_size is too small): correct fp32 tiled GEMM
__global__ void gemm_f32_fallback(const float* __restrict__ A, const float* __restrict__ B,
                                  float* __restrict__ C, int M, int N, int K) {
    __shared__ float As[16][17];
    __shared__ float Bs[16][17];
    int tx = threadIdx.x & 15;
    int ty = threadIdx.x >> 4;
    int row = blockIdx.y * 16 + ty;
    int col = blockIdx.x * 16 + tx;
    float s = 0.f;
    for (int k0 = 0; k0 < K; k0 += 16) {
        As[ty][tx] = A[(long)row * K + k0 + tx];
        Bs[ty][tx] = B[(long)(k0 + ty) * N + col];
        __syncthreads();
#pragma unroll
        for (int kk = 0; kk < 16; ++kk) s += As[ty][kk] * Bs[kk][tx];
        __syncthreads();
    }
    C[(long)row * N + col] = s;
}

extern "C" void kernel_launch(void* const* d_in, const int* in_sizes, int n_in,
                              void* d_out, int out_size, void* d_ws, size_t ws_size,
                              hipStream_t stream) {
    const int M = 8192, K = 4096, N = 4096;
    const float* x = (const float*)d_in[0];       // [M][K] fp32
    const float* wte = (const float*)d_in[1];     // [K][N] fp32
    float* out = (float*)d_out;                   // [M][N] fp32

    const size_t need = (size_t)M * K * 2 + (size_t)K * N * 2;  // 96 MiB
    if (ws_size >= need) {
        u16* xb = (u16*)d_ws;                  // [M][K] bf16
        u16* wt = xb + (size_t)M * K;          // [N][K] bf16 (transposed)

        cvt_f32_to_bf16<<<2048, 256, 0, stream>>>(x, xb, (long)M * K / 8);

        dim3 tg(N / 32, K / 32);
        transpose_cvt<<<tg, 256, 0, stream>>>(wte, wt, K, N);

        const int nblocks = (M / 256) * (N / 256);   // 512
        gemm_bf16_256<<<nblocks, 512, 0, stream>>>(xb, wt, out);
    } else {
        dim3 g(N / 16, M / 16);
        gemm_f32_fallback<<<g, 256, 0, stream>>>(x, wte, out, M, N, K);
    }
}

// Round 5
// 267.109 us; speedup vs baseline: 1.7467x; 1.7467x over previous
//
#include <hip/hip_runtime.h>
#include <hip/hip_bf16.h>

typedef unsigned short u16;
typedef __bf16 bf16x8 __attribute__((ext_vector_type(8)));
typedef float f32x4 __attribute__((ext_vector_type(4)));

static __device__ __forceinline__ u16 f2b(float f) {
    __hip_bfloat16 h = __float2bfloat16(f);
    union { __hip_bfloat16 b; u16 u; } c;
    c.b = h;
    return c.u;
}

// fp32 -> bf16 bits, 8 elements per thread-iter
__global__ void cvt_f32_to_bf16(const float* __restrict__ in, u16* __restrict__ out, long n8) {
    long i = (long)blockIdx.x * blockDim.x + threadIdx.x;
    long stride = (long)gridDim.x * blockDim.x;
    for (long v = i; v < n8; v += stride) {
        const float4* p = reinterpret_cast<const float4*>(in) + 2 * v;
        float4 a = p[0];
        float4 b = p[1];
        uint4 o;
        o.x = (unsigned)f2b(a.x) | ((unsigned)f2b(a.y) << 16);
        o.y = (unsigned)f2b(a.z) | ((unsigned)f2b(a.w) << 16);
        o.z = (unsigned)f2b(b.x) | ((unsigned)f2b(b.y) << 16);
        o.w = (unsigned)f2b(b.z) | ((unsigned)f2b(b.w) << 16);
        reinterpret_cast<uint4*>(out)[v] = o;
    }
}

// W[K][N] fp32 -> Wt[N][K] bf16 bits, 32x32 LDS-tiled transpose
__global__ void transpose_cvt(const float* __restrict__ w, u16* __restrict__ wt, int K, int N) {
    __shared__ float tile[32][33];
    int bn = blockIdx.x * 32;
    int bk = blockIdx.y * 32;
    int tx = threadIdx.x & 31;
    int ty = threadIdx.x >> 5;
#pragma unroll
    for (int i = 0; i < 32; i += 8)
        tile[ty + i][tx] = w[(long)(bk + ty + i) * N + bn + tx];
    __syncthreads();
#pragma unroll
    for (int i = 0; i < 32; i += 8)
        wt[(long)(bn + ty + i) * K + bk + tx] = f2b(tile[tx][ty + i]);
}

static __device__ __forceinline__ void gl_lds16(const u16* g, u16* l) {
    __builtin_amdgcn_global_load_lds(
        (const __attribute__((address_space(1))) void*)g,
        (__attribute__((address_space(3))) void*)l, 16, 0, 0);
}

// ---------------------------------------------------------------------------
// 256x256 8-phase bf16 GEMM (R3 skeleton). C = A[8192][4096] * Wt[4096][4096]^T
// 512 threads = 8 waves (2M x 4N), per-wave 128x64, BK=64, 64 K-tiles.
// R5 delta vs R3 (sync skeleton UNCHANGED: 2 barriers/phase, lgkmcnt(0)
// before each MFMA cluster, vmcnt(4) once per tile at p3-end, no sched_barrier):
//   b23 reads (4) issue inside p0's MFMA region; a47 reads (8) inside p1's.
//   Their LDS drain overlaps the MFMA epochs; consuming phase's lgkmcnt(0)
//   still guards completion. All moved reads are same-tile (no vmcnt change).
// Hazards: b23 reads complete < p1 lgkm0 < p2's STG-B h0 issue (WAR ok);
//   STG-A writes OB only (no intra-buffer A WAR); RAW staging unchanged.
// T2 3-bit XOR swizzle (conflicts measured 0), T1 XCD swizzle kept.
// ---------------------------------------------------------------------------
#define GK 4096L

#define STG(srcbase, dstbase, hh, ktel)                                              \
    gl_lds16((srcbase) + (long)((hh) * 128) * GK + (ktel), (u16*)((dstbase) + (hh) * 16384)); \
    gl_lds16((srcbase) + (long)((hh) * 128 + 64) * GK + (ktel), (u16*)((dstbase) + (hh) * 16384 + 8192));

#define RD_A03(buf)                                                                  \
    _Pragma("unroll") for (int mi = 0; mi < 4; ++mi)                                 \
        _Pragma("unroll") for (int kk = 0; kk < 2; ++kk)                             \
            a03[mi][kk] = *(const bf16x8*)((buf) + abase + mi * 2048 + (lcol ^ (kk * 64)));
#define RD_A47(buf)                                                                  \
    _Pragma("unroll") for (int mi = 0; mi < 4; ++mi)                                 \
        _Pragma("unroll") for (int kk = 0; kk < 2; ++kk)                             \
            a47[mi][kk] = *(const bf16x8*)((buf) + abase + (mi + 4) * 2048 + (lcol ^ (kk * 64)));
#define RD_B23(buf)                                                                  \
    _Pragma("unroll") for (int ni = 0; ni < 2; ++ni)                                 \
        _Pragma("unroll") for (int kk = 0; kk < 2; ++kk)                             \
            b23[ni][kk] = *(const bf16x8*)((buf) + bbase + (ni + 2) * 2048 + (lcol ^ (kk * 64)));
#define RD_B01(buf)                                                                  \
    _Pragma("unroll") for (int ni = 0; ni < 2; ++ni)                                 \
        _Pragma("unroll") for (int kk = 0; kk < 2; ++kk)                             \
            b01[ni][kk] = *(const bf16x8*)((buf) + bbase + ni * 2048 + (lcol ^ (kk * 64)));

#define MFMA_Q(AR, BR, MO, NO)                                                       \
    _Pragma("unroll") for (int mi = 0; mi < 4; ++mi)                                 \
        _Pragma("unroll") for (int ni = 0; ni < 2; ++ni)                             \
            _Pragma("unroll") for (int kk = 0; kk < 2; ++kk)                         \
                acc[(MO) + mi][(NO) + ni] = __builtin_amdgcn_mfma_f32_16x16x32_bf16( \
                    AR[mi][kk], BR[ni][kk], acc[(MO) + mi][(NO) + ni], 0, 0, 0);

#define PRIO1 __builtin_amdgcn_s_setprio(1);
#define PRIO0 __builtin_amdgcn_s_setprio(0);
#define BAR   __builtin_amdgcn_s_barrier();
#define LGKM0 asm volatile("s_waitcnt lgkmcnt(0)");

#define KTILE(CB, OB, SA, SB, VMP, KTA, KTB) do {                                    \
    char* cb = shb + (CB) * 65536;                                                   \
    /* p0: read a03+b01 (12); STG-A h0; MFMA q0; b23 reads interleave w/ MFMA */     \
    RD_A03(cb)                                                                       \
    RD_B01(cb)                                                                       \
    if (SA) { STG(Asrc, ldsAt + (OB) * 65536, 0, KTA) }                              \
    BAR LGKM0 PRIO1                                                                  \
    MFMA_Q(a03, b01, 0, 0)                                                           \
    RD_B23(cb)                                                                       \
    PRIO0 BAR                                                                        \
    /* p1: STG-A h1; MFMA q1 (a03 x b23); a47 reads interleave w/ MFMA */            \
    if (SA) { STG(Asrc, ldsAt + (OB) * 65536, 1, KTA) }                              \
    BAR LGKM0 PRIO1                                                                  \
    MFMA_Q(a03, b23, 0, 2)                                                           \
    RD_A47(cb)                                                                       \
    PRIO0 BAR                                                                        \
    /* p2: STG-B h0; MFMA q2 (a47 x b23) */                                          \
    if (SB) { STG(Bsrc, ldsBt + (CB) * 65536, 0, KTB) }                              \
    BAR LGKM0 PRIO1                                                                  \
    MFMA_Q(a47, b23, 4, 2)                                                           \
    PRIO0 BAR                                                                        \
    /* p3: STG-B h1; MFMA q3 (a47 x b01); boundary vmcnt */                          \
    if (SB) { STG(Bsrc, ldsBt + (CB) * 65536, 1, KTB) }                              \
    BAR LGKM0 PRIO1                                                                  \
    MFMA_Q(a47, b01, 4, 0)                                                           \
    PRIO0                                                                            \
    asm volatile("s_waitcnt vmcnt(" VMP ")" ::: "memory");                           \
    BAR                                                                              \
} while (0)

__global__ __launch_bounds__(512, 2) void gemm_bf16_256(
    const u16* __restrict__ A, const u16* __restrict__ Bt, float* __restrict__ C) {
    __shared__ __align__(16) u16 sh[2][2][256][64];   // [buf][A/B][row][col] = 128 KiB
    char* shb = (char*)&sh[0][0][0][0];

    const int t = threadIdx.x;
    const int lane = t & 63;
    const int wid = t >> 6;
    const int wr = wid >> 2;   // 0..1
    const int wc = wid & 3;    // 0..3

    // T1: bijective XCD swizzle (512 wgs, 512 % 8 == 0)
    const int bid = blockIdx.x;
    const int wg = (bid & 7) * 64 + (bid >> 3);
    const int tm = wg >> 4;          // 0..31
    const int tn = wg & 15;          // 0..15

    // staging source: thread t -> LDS physical (row = t>>3, colblk = t&7);
    // physical colblk holds logical (t&7) ^ (row&7)  [T2 involution]
    const int srow = t >> 3;
    const int scol = (((t & 7) ^ ((t >> 3) & 7)) * 8);
    const u16* Asrc = A + (long)(tm * 256 + srow) * GK + scol;
    const u16* Bsrc = Bt + (long)(tn * 256 + srow) * GK + scol;
    char* ldsAt = shb + t * 16;
    char* ldsBt = shb + 32768 + t * 16;

    // ds_read lane addressing: same involution; K-half folds in via ^(kk*64)
    const int lrow = lane & 15;
    const int lcol = (((lane >> 4) ^ (lrow & 7)) << 4);
    const int abase = (wr * 128 + lrow) * 128;
    const int bbase = 32768 + (wc * 64 + lrow) * 128;

    f32x4 acc[8][4] = {};
    bf16x8 a03[4][2], a47[4][2], b23[2][2], b01[2][2];

    // prologue: B(0)->buf0, A(0)->buf0, B(1)->buf1 (12 loads);
    // vmcnt(4) leaves B(1)'s 4 in flight -> A(0),B(0) resident.
    STG(Bsrc, ldsBt, 0, 0)
    STG(Bsrc, ldsBt, 1, 0)
    STG(Asrc, ldsAt, 0, 0)
    STG(Asrc, ldsAt, 1, 0)
    STG(Bsrc, ldsBt + 65536, 0, 64)
    STG(Bsrc, ldsBt + 65536, 1, 64)
    asm volatile("s_waitcnt vmcnt(4)" ::: "memory");
    BAR

    // tiles 0..61 (pairs), then t62 (stage A(63) only, vmcnt 0), t63 (drain)
#pragma unroll 1
    for (int it = 0; it < 31; ++it) {
        const long kt = (long)it * 128;
        KTILE(0, 1, 1, 1, "4", kt + 64, kt + 128);
        KTILE(1, 0, 1, 1, "4", kt + 128, kt + 192);
    }
    KTILE(0, 1, 1, 0, "0", 4032, 0);
    KTILE(1, 0, 0, 0, "0", 0, 0);

    // epilogue: C/D layout col=lane&15, row=(lane>>4)*4+j
    const int crow = (lane >> 4) * 4;
    const int ccol = lane & 15;
    float* Cp = C + (long)(tm * 256 + wr * 128 + crow) * 4096 + tn * 256 + wc * 64 + ccol;
#pragma unroll
    for (int mi = 0; mi < 8; ++mi) {
#pragma unroll
        for (int j = 0; j < 4; ++j) {
            float* r = Cp + (long)(mi * 16 + j) * 4096;
#pragma unroll
            for (int ni = 0; ni < 4; ++ni)
                r[ni * 16] = acc[mi][ni][j];
        }
    }
}

// fallback (only if ws_size is too small): correct fp32 tiled GEMM
__global__ void gemm_f32_fallback(const float* __restrict__ A, const float* __restrict__ B,
                                  float* __restrict__ C, int M, int N, int K) {
    __shared__ float As[16][17];
    __shared__ float Bs[16][17];
    int tx = threadIdx.x & 15;
    int ty = threadIdx.x >> 4;
    int row = blockIdx.y * 16 + ty;
    int col = blockIdx.x * 16 + tx;
    float s = 0.f;
    for (int k0 = 0; k0 < K; k0 += 16) {
        As[ty][tx] = A[(long)row * K + k0 + tx];
        Bs[ty][tx] = B[(long)(k0 + ty) * N + col];
        __syncthreads();
#pragma unroll
        for (int kk = 0; kk < 16; ++kk) s += As[ty][kk] * Bs[kk][tx];
        __syncthreads();
    }
    C[(long)row * N + col] = s;
}

extern "C" void kernel_launch(void* const* d_in, const int* in_sizes, int n_in,
                              void* d_out, int out_size, void* d_ws, size_t ws_size,
                              hipStream_t stream) {
    const int M = 8192, K = 4096, N = 4096;
    const float* x = (const float*)d_in[0];       // [M][K] fp32
    const float* wte = (const float*)d_in[1];     // [K][N] fp32
    float* out = (float*)d_out;                   // [M][N] fp32

    const size_t need = (size_t)M * K * 2 + (size_t)K * N * 2;  // 96 MiB
    if (ws_size >= need) {
        u16* xb = (u16*)d_ws;                  // [M][K] bf16
        u16* wt = xb + (size_t)M * K;          // [N][K] bf16 (transposed)

        cvt_f32_to_bf16<<<2048, 256, 0, stream>>>(x, xb, (long)M * K / 8);

        dim3 tg(N / 32, K / 32);
        transpose_cvt<<<tg, 256, 0, stream>>>(wte, wt, K, N);

        const int nblocks = (M / 256) * (N / 256);   // 512
        gemm_bf16_256<<<nblocks, 512, 0, stream>>>(xb, wt, out);
    } else {
        dim3 g(N / 16, M / 16);
        gemm_f32_fallback<<<g, 256, 0, stream>>>(x, wte, out, M, N, K);
    }
}